// Round 2
// baseline (383.900 us; speedup 1.0000x reference)
//
#include <hip/hip_runtime.h>

typedef unsigned short ushort_t;
typedef __attribute__((ext_vector_type(8))) short short8;
typedef __attribute__((ext_vector_type(4))) float f32x4;

#define AS1(p) ((const __attribute__((address_space(1))) void*)(p))
#define AS3(p) ((__attribute__((address_space(3))) void*)(p))

__device__ __forceinline__ ushort_t f2bf(float f){
  unsigned u = __float_as_uint(f);
  u += 0x7FFFu + ((u>>16)&1u);
  return (ushort_t)(u>>16);
}
__device__ __forceinline__ float bf2f(ushort_t h){
  return __uint_as_float(((unsigned)h)<<16);
}

// ---------------------------------------------------------------- conv fp32->bf16
__global__ __launch_bounds__(256) void conv_f2b(const float* __restrict__ src,
                                                ushort_t* __restrict__ dst, int n){
  int i = (blockIdx.x*256 + threadIdx.x)*4;
  if (i < n){
    float4 v = *(const float4*)&src[i];
    ushort_t o0=f2bf(v.x), o1=f2bf(v.y), o2=f2bf(v.z), o3=f2bf(v.w);
    ushort4 o; o.x=o0; o.y=o1; o.z=o2; o.w=o3;
    *(ushort4*)&dst[i] = o;
  }
}

// ---------------------------------------------------------------- LoRA h = X @ A0^T * (da*db)
template<bool BF16IN>
__global__ __launch_bounds__(256) void lora_h(const void* __restrict__ X,
                                              const float* __restrict__ A0,
                                              const float* __restrict__ da,
                                              const float* __restrict__ db,
                                              float* __restrict__ out, int K){
  int m = blockIdx.x;
  int tid = threadIdx.x, lane = tid & 63, w = tid >> 6;
  float part[8] = {0,0,0,0,0,0,0,0};
  for (int k = tid; k < K; k += 256){
    float xv;
    if (BF16IN) xv = bf2f(((const ushort_t*)X)[(size_t)m*K + k]);
    else        xv = ((const float*)X)[(size_t)m*K + k];
    #pragma unroll
    for (int r=0;r<8;++r) part[r] += xv * A0[r*K + k];
  }
  #pragma unroll
  for (int r=0;r<8;++r)
    for (int d=1;d<64;d<<=1) part[r] += __shfl_xor(part[r], d, 64);
  __shared__ float wsum[4][8];
  if (lane==0){
    #pragma unroll
    for (int r=0;r<8;++r) wsum[w][r] = part[r];
  }
  __syncthreads();
  if (tid < 8){
    float s = wsum[0][tid]+wsum[1][tid]+wsum[2][tid]+wsum[3][tid];
    out[(size_t)m*8 + tid] = s * da[tid]*db[tid];
  }
}

// ---------------------------------------------------------------- GEMM + LoRA epilogue
// C[m,n] = sum_k A[m,k]*Bw[n,k]  + 0.125 * sum_r h[m,r]*B0[n,r]
// MODE 0: store bf16 ; MODE 1: store f32
template<int MODE>
__global__ __launch_bounds__(256) void gemm_lora(const ushort_t* __restrict__ A,
                                                 const ushort_t* __restrict__ Bw,
                                                 const float* __restrict__ hmat,
                                                 const float* __restrict__ B0,
                                                 void* __restrict__ C,
                                                 int M, int N, int K){
  __shared__ __align__(16) ushort_t As[128*32];
  __shared__ __align__(16) ushort_t Bs[128*32];
  __shared__ float hs[128][8];
  __shared__ float b0s[128][8];

  const int tid = threadIdx.x, lane = tid & 63, w = tid >> 6;
  const int wr = w >> 1, wc = w & 1;
  const int m0 = blockIdx.y*128, n0 = blockIdx.x*128;

  for (int i = tid; i < 128*8; i += 256) hs[i>>3][i&7]  = hmat[(size_t)(m0 + (i>>3))*8 + (i&7)];
  for (int i = tid; i < 128*8; i += 256) b0s[i>>3][i&7] = B0[(size_t)(n0 + (i>>3))*8 + (i&7)];

  f32x4 acc[4][4] = {};

  for (int k0 = 0; k0 < K; k0 += 32){
    __syncthreads();
    #pragma unroll
    for (int i=0;i<2;++i){
      int c = (w*2+i)*64 + lane;
      const ushort_t* ga = A  + (size_t)(m0 + (c>>2))*K + k0 + (c&3)*8;
      __builtin_amdgcn_global_load_lds(AS1(ga), AS3(As + (w*2+i)*512), 16, 0, 0);
      const ushort_t* gb = Bw + (size_t)(n0 + (c>>2))*K + k0 + (c&3)*8;
      __builtin_amdgcn_global_load_lds(AS1(gb), AS3(Bs + (w*2+i)*512), 16, 0, 0);
    }
    __syncthreads();
    short8 af[4], bf[4];
    #pragma unroll
    for (int m=0;m<4;++m) af[m] = *(const short8*)&As[(wr*64 + m*16 + (lane&15))*32 + (lane>>4)*8];
    #pragma unroll
    for (int n=0;n<4;++n) bf[n] = *(const short8*)&Bs[(wc*64 + n*16 + (lane&15))*32 + (lane>>4)*8];
    #pragma unroll
    for (int m=0;m<4;++m)
      #pragma unroll
      for (int n=0;n<4;++n)
        acc[m][n] = __builtin_amdgcn_mfma_f32_16x16x32_bf16(af[m], bf[n], acc[m][n], 0, 0, 0);
  }

  // epilogue: LoRA add + store
  float b0r[4][8];
  #pragma unroll
  for (int n=0;n<4;++n){
    int cl = wc*64 + n*16 + (lane&15);
    #pragma unroll
    for (int r=0;r<8;++r) b0r[n][r] = b0s[cl][r];
  }
  #pragma unroll
  for (int m=0;m<4;++m){
    #pragma unroll
    for (int j=0;j<4;++j){
      int rl = wr*64 + m*16 + (lane>>4)*4 + j;
      float hr[8];
      #pragma unroll
      for (int r=0;r<8;++r) hr[r] = hs[rl][r];
      #pragma unroll
      for (int n=0;n<4;++n){
        int cl = wc*64 + n*16 + (lane&15);
        float lor = 0.f;
        #pragma unroll
        for (int r=0;r<8;++r) lor += hr[r]*b0r[n][r];
        float v = acc[m][n][j] + 0.125f*lor;
        size_t idx = (size_t)(m0+rl)*N + (n0+cl);
        if (MODE==0) ((ushort_t*)C)[idx] = f2bf(v);
        else         ((float*)C)[idx]    = v;
      }
    }
  }
}

// ---------------------------------------------------------------- RoPE (in place on qkv bf16)
// qkv: [B*T][6144], rope applies to s in {0,1}, dims 0..15 of each head
__global__ __launch_bounds__(256) void rope_kernel(ushort_t* __restrict__ qkv,
                                                   const float* __restrict__ cosb,
                                                   const float* __restrict__ sinb){
  int idx = blockIdx.x*256 + threadIdx.x;   // 0 .. 1048575
  int d = idx & 7;
  int g = idx >> 3;                          // 0 .. 131071
  int h_ = g & 15;
  int s  = (g>>4) & 1;
  int t  = (g>>5) & 511;
  int b  = g >> 14;
  size_t base = (size_t)(b*512 + t)*6144 + s*2048 + h_*128;
  float x1 = bf2f(qkv[base+d]), x2 = bf2f(qkv[base+d+8]);
  float c = cosb[t*8+d], sn = sinb[t*8+d];
  qkv[base+d]   = f2bf(x1*c - x2*sn);
  qkv[base+d+8] = f2bf(x2*c + x1*sn);
}

// ---------------------------------------------------------------- flash attention
// grid: (T/64, H, B). block 256 = 4 waves, wave w owns q rows [qb0+w*16, +16)
__global__ __launch_bounds__(256) void attn_kernel(const ushort_t* __restrict__ qkv,
                                                   ushort_t* __restrict__ y){
  __shared__ __align__(16) ushort_t Ks[32*128];     // [kvrow][dim]
  __shared__ __align__(16) ushort_t Vt[128*32];     // [dim][kvrow]
  __shared__ __align__(16) ushort_t Pl[4][16][32];  // per-wave P tile

  const int qt = blockIdx.x, hh = blockIdx.y, b = blockIdx.z;
  const int tid = threadIdx.x, lane = tid & 63, w = tid >> 6;
  const int qb0 = qt*64;
  const int row_base = b*512;
  const int qoff = hh*128;
  const int koff = 2048 + hh*128;
  const int voff = 4096 + hh*128;
  const float scale = 0.08838834764831845f; // 1/sqrt(128)

  // Q fragments (A operand), once
  short8 qf[4];
  {
    int qr = qb0 + w*16 + (lane & 15);
    const ushort_t* qp = qkv + (size_t)(row_base + qr)*6144 + qoff + (lane>>4)*8;
    #pragma unroll
    for (int kc=0;kc<4;++kc) qf[kc] = *(const short8*)(qp + kc*32);
  }

  f32x4 o[8] = {};
  float mrow[4] = {-1e30f,-1e30f,-1e30f,-1e30f};
  float lrow[4] = {0,0,0,0};

  const int ntiles = qb0/32 + 2;
  const int wmax = qb0 + w*16 + 15;

  for (int t = 0; t < ntiles; ++t){
    int kv0 = t*32;
    __syncthreads();
    // stage K [32][128] via global_load_lds
    #pragma unroll
    for (int i=0;i<2;++i){
      int c = (w*2+i)*64 + lane;
      const ushort_t* g = qkv + (size_t)(row_base + kv0 + (c>>4))*6144 + koff + (c&15)*8;
      __builtin_amdgcn_global_load_lds(AS1(g), AS3(Ks + (w*2+i)*512), 16, 0, 0);
    }
    // stage V transposed: Vt[dim][kvrow]
    {
      int r = tid >> 3, d0 = (tid & 7)*16;
      const ushort_t* g = qkv + (size_t)(row_base + kv0 + r)*6144 + voff + d0;
      short8 v0 = *(const short8*)g;
      short8 v1 = *(const short8*)(g + 8);
      #pragma unroll
      for (int ii=0; ii<8; ++ii) Vt[(d0+ii)*32 + r]   = (ushort_t)v0[ii];
      #pragma unroll
      for (int ii=0; ii<8; ++ii) Vt[(d0+8+ii)*32 + r] = (ushort_t)v1[ii];
    }
    __syncthreads();
    if (kv0 > wmax) continue;

    // QK^T : 2 col-groups x 4 k-chunks
    f32x4 s[2] = {};
    #pragma unroll
    for (int cg=0;cg<2;++cg)
      #pragma unroll
      for (int kc=0;kc<4;++kc){
        short8 kf = *(const short8*)&Ks[(cg*16 + (lane&15))*128 + kc*32 + (lane>>4)*8];
        s[cg] = __builtin_amdgcn_mfma_f32_16x16x32_bf16(qf[kc], kf, s[cg], 0, 0, 0);
      }

    // online softmax
    float fac[4], p0[4], p1[4];
    #pragma unroll
    for (int j=0;j<4;++j){
      int qr = qb0 + w*16 + (lane>>4)*4 + j;
      float a0 = s[0][j]*scale; if (kv0 + (lane&15) > qr)      a0 = -1e30f;
      float a1 = s[1][j]*scale; if (kv0 + 16 + (lane&15) > qr) a1 = -1e30f;
      float mx = fmaxf(a0, a1);
      for (int d=1; d<16; d<<=1) mx = fmaxf(mx, __shfl_xor(mx, d, 16));
      float mn = fmaxf(mrow[j], mx);
      float f  = __expf(mrow[j] - mn);
      mrow[j] = mn;
      p0[j] = __expf(a0 - mn);
      p1[j] = __expf(a1 - mn);
      float rs = p0[j] + p1[j];
      for (int d=1; d<16; d<<=1) rs += __shfl_xor(rs, d, 16);
      lrow[j] = lrow[j]*f + rs;
      fac[j] = f;
    }
    #pragma unroll
    for (int n=0;n<8;++n){
      #pragma unroll
      for (int j=0;j<4;++j) o[n][j] *= fac[j];
    }
    // write P (bf16) to per-wave LDS, re-read as A fragment
    #pragma unroll
    for (int j=0;j<4;++j){
      Pl[w][(lane>>4)*4+j][(lane&15)]      = f2bf(p0[j]);
      Pl[w][(lane>>4)*4+j][16+(lane&15)]   = f2bf(p1[j]);
    }
    short8 pf = *(const short8*)&Pl[w][lane&15][(lane>>4)*8];
    #pragma unroll
    for (int n=0;n<8;++n){
      short8 vf = *(const short8*)&Vt[(n*16 + (lane&15))*32 + (lane>>4)*8];
      o[n] = __builtin_amdgcn_mfma_f32_16x16x32_bf16(pf, vf, o[n], 0, 0, 0);
    }
  }

  // epilogue: normalize and store y[b*512+qr][hh*128 + d]
  #pragma unroll
  for (int j=0;j<4;++j){
    float inv = 1.0f / lrow[j];
    int qr = qb0 + w*16 + (lane>>4)*4 + j;
    #pragma unroll
    for (int n=0;n<8;++n)
      y[(size_t)(row_base+qr)*2048 + hh*128 + n*16 + (lane&15)] = f2bf(o[n][j]*inv);
  }
}

// ---------------------------------------------------------------- launch
extern "C" void kernel_launch(void* const* d_in, const int* in_sizes, int n_in,
                              void* d_out, int out_size, void* d_ws, size_t ws_size,
                              hipStream_t stream){
  const float* x       = (const float*)d_in[0];
  const float* Wqkv    = (const float*)d_in[1];
  const float* A0_qkv  = (const float*)d_in[2];
  const float* B0_qkv  = (const float*)d_in[3];
  const float* da_qkv  = (const float*)d_in[4];
  const float* db_qkv  = (const float*)d_in[5];
  const float* Wout    = (const float*)d_in[6];
  const float* A0_out  = (const float*)d_in[7];
  const float* B0_out  = (const float*)d_in[8];
  const float* da_out  = (const float*)d_in[9];
  const float* db_out  = (const float*)d_in[10];
  const float* cosb    = (const float*)d_in[11];
  const float* sinb    = (const float*)d_in[12];
  float* out = (float*)d_out;

  char* ws = (char*)d_ws;
  ushort_t* x_bf    = (ushort_t*)(ws);                       // 16,777,216 B
  ushort_t* wqkv_bf = (ushort_t*)(ws + 16777216);            // 25,165,824 B
  ushort_t* wout_bf = (ushort_t*)(ws + 41943040);            //  8,388,608 B
  ushort_t* qkv_bf  = (ushort_t*)(ws + 50331648);            // 50,331,648 B
  ushort_t* y_bf    = (ushort_t*)(ws + 100663296);           // 16,777,216 B
  float*    h_qkv   = (float*)   (ws + 117440512);           //    131,072 B
  float*    h_out   = (float*)   (ws + 117571584);           //    131,072 B

  const int M = 4096;      // B*T
  const int C = 2048;
  const int N3 = 6144;

  conv_f2b<<<8192, 256, 0, stream>>>(x,    x_bf,    M*C);
  conv_f2b<<<12288,256, 0, stream>>>(Wqkv, wqkv_bf, N3*C);
  conv_f2b<<<4096, 256, 0, stream>>>(Wout, wout_bf, C*C);

  lora_h<false><<<M, 256, 0, stream>>>(x, A0_qkv, da_qkv, db_qkv, h_qkv, C);

  gemm_lora<0><<<dim3(N3/128, M/128), 256, 0, stream>>>(x_bf, wqkv_bf, h_qkv, B0_qkv,
                                                        qkv_bf, M, N3, C);

  rope_kernel<<<4096, 256, 0, stream>>>(qkv_bf, cosb, sinb);

  attn_kernel<<<dim3(8, 16, 8), 256, 0, stream>>>(qkv_bf, y_bf);

  lora_h<true><<<M, 256, 0, stream>>>(y_bf, A0_out, da_out, db_out, h_out, C);

  gemm_lora<1><<<dim3(C/128, M/128), 256, 0, stream>>>(y_bf, wout_bf, h_out, B0_out,
                                                       out, M, C, C);
}

// Round 5
// 331.985 us; speedup vs baseline: 1.1564x; 1.1564x over previous
//
#include <hip/hip_runtime.h>

typedef unsigned short ushort_t;
typedef __attribute__((ext_vector_type(8))) short short8;
typedef __attribute__((ext_vector_type(4))) float f32x4;

#define AS1(p) ((const __attribute__((address_space(1))) void*)(p))
#define AS3(p) ((__attribute__((address_space(3))) void*)(p))

__device__ __forceinline__ ushort_t f2bf(float f){
  unsigned u = __float_as_uint(f);
  u += 0x7FFFu + ((u>>16)&1u);
  return (ushort_t)(u>>16);
}
__device__ __forceinline__ float bf2f(ushort_t h){
  return __uint_as_float(((unsigned)h)<<16);
}

// ---------------------------------------------------------------- conv fp32->bf16
__global__ __launch_bounds__(256) void conv_f2b(const float* __restrict__ src,
                                                ushort_t* __restrict__ dst, int n){
  int i = (blockIdx.x*256 + threadIdx.x)*4;
  if (i < n){
    float4 v = *(const float4*)&src[i];
    ushort_t o0=f2bf(v.x), o1=f2bf(v.y), o2=f2bf(v.z), o3=f2bf(v.w);
    ushort4 o; o.x=o0; o.y=o1; o.z=o2; o.w=o3;
    *(ushort4*)&dst[i] = o;
  }
}

// ---------------------------------------------------------------- LoRA h = X @ A0^T * (da*db)
template<bool BF16IN>
__global__ __launch_bounds__(256) void lora_h(const void* __restrict__ X,
                                              const float* __restrict__ A0,
                                              const float* __restrict__ da,
                                              const float* __restrict__ db,
                                              float* __restrict__ out, int K){
  int m = blockIdx.x;
  int tid = threadIdx.x, lane = tid & 63, w = tid >> 6;
  float part[8] = {0,0,0,0,0,0,0,0};
  for (int k = tid; k < K; k += 256){
    float xv;
    if (BF16IN) xv = bf2f(((const ushort_t*)X)[(size_t)m*K + k]);
    else        xv = ((const float*)X)[(size_t)m*K + k];
    #pragma unroll
    for (int r=0;r<8;++r) part[r] += xv * A0[r*K + k];
  }
  #pragma unroll
  for (int r=0;r<8;++r)
    for (int d=1;d<64;d<<=1) part[r] += __shfl_xor(part[r], d, 64);
  __shared__ float wsum[4][8];
  if (lane==0){
    #pragma unroll
    for (int r=0;r<8;++r) wsum[w][r] = part[r];
  }
  __syncthreads();
  if (tid < 8){
    float s = wsum[0][tid]+wsum[1][tid]+wsum[2][tid]+wsum[3][tid];
    out[(size_t)m*8 + tid] = s * da[tid]*db[tid];
  }
}

// ---------------------------------------------------------------- 256x256 8-phase GEMM + LoRA (bf16 out)
// C[m,n] = sum_k A[m,k]*Bw[n,k] + 0.125 * sum_r h[m,r]*B0[n,r]
// 512 threads = 8 waves (2M x 4N). BK=64. LDS 128KB double-buffered.
// Wave (wm,wn): m-fragment q at tile row q*32+wm*16 (q=0..7); n-fragment r at col r*64+wn*16 (r=0..3).
// Phases per K-tile: P0: q0-3 x r0-1 | P1: q4-7 x r0-1 | P2: q0-3 x r2-3 | P3: q4-7 x r2-3
// Staging (tile t+1, into buf^1): P0->A-half0, P1->B-half0, P2->A-half1, P3->B-half1.
// Counted waits: vmcnt(4) at end of P0,P1,P3 (each ensures a half staged 3-4 phases earlier).
__global__ __launch_bounds__(512, 2) void gemm256_lora(
    const ushort_t* __restrict__ A, const ushort_t* __restrict__ Bw,
    const float* __restrict__ hmat, const float* __restrict__ B0,
    ushort_t* __restrict__ C, int M, int N, int K)
{
  __shared__ __align__(16) char smem[131072];
  const int tid = threadIdx.x, lane = tid & 63, w = tid >> 6;
  const int wm = w >> 2, wn = w & 3;

  // XCD-aware bijective swizzle (grid % 8 == 0)
  const int nbn = N >> 8;
  const int nwg = (M >> 8) * nbn;
  const int q8 = nwg >> 3;
  const int swz = ((int)blockIdx.x & 7)*q8 + ((int)blockIdx.x >> 3);
  const int m0 = (swz / nbn) << 8, n0 = (swz % nbn) << 8;

  const int NTt = K >> 6;

  // staging geometry: wave w stages 2x 1KB chunks per half-tile.
  // LDS linear dest; global source pre-permuted with the read swizzle (chunk ^= row&7).
  const int srow   = w*16 + (lane>>3);          // row of j=0 chunk within half (j=1 adds +8)
  const int schunk = (lane&7) ^ (lane>>3);      // row&7 == lane>>3 for j=0 and j=1

  #define STAGE_A(h, tt, b) do { \
    const ushort_t* g0_ = A + (size_t)(m0 + (h)*128 + srow)*K + (tt)*64 + schunk*8; \
    __builtin_amdgcn_global_load_lds(AS1(g0_), AS3(smem + (b)*32768 + (h)*16384 + (w*2+0)*1024), 16, 0, 0); \
    __builtin_amdgcn_global_load_lds(AS1(g0_ + (size_t)8*K), AS3(smem + (b)*32768 + (h)*16384 + (w*2+1)*1024), 16, 0, 0); \
  } while(0)
  #define STAGE_B(h, tt, b) do { \
    const ushort_t* g0_ = Bw + (size_t)(n0 + (h)*128 + srow)*K + (tt)*64 + schunk*8; \
    __builtin_amdgcn_global_load_lds(AS1(g0_), AS3(smem + 65536 + (b)*32768 + (h)*16384 + (w*2+0)*1024), 16, 0, 0); \
    __builtin_amdgcn_global_load_lds(AS1(g0_ + (size_t)8*K), AS3(smem + 65536 + (b)*32768 + (h)*16384 + (w*2+1)*1024), 16, 0, 0); \
  } while(0)

  // swizzled ds_read of one 16B fragment chunk (row&7 == lane&7 for all fragments)
  #define RDA(b, q, kk) (*(const short8*)(smem + (b)*32768 + \
      ((q)*32 + wm*16 + (lane&15))*128 + ((((kk)*4 + (lane>>4)) ^ (lane&7))<<4)))
  #define RDB(b, r, kk) (*(const short8*)(smem + 65536 + (b)*32768 + \
      ((r)*64 + wn*16 + (lane&15))*128 + ((((kk)*4 + (lane>>4)) ^ (lane&7))<<4)))

  #define MM(q,r) do{ \
    acc[q][r] = __builtin_amdgcn_mfma_f32_16x16x32_bf16(aF[q][0], bF[r][0], acc[q][r], 0,0,0); \
    acc[q][r] = __builtin_amdgcn_mfma_f32_16x16x32_bf16(aF[q][1], bF[r][1], acc[q][r], 0,0,0); \
  }while(0)

  #define BARRIER() asm volatile("s_barrier" ::: "memory")

  short8 aF[8][2];
  short8 bF[4][2];
  f32x4 acc[8][4] = {};

  // prologue: stage tile 0 (FIFO order A0,B0,A1,B1), wait for A0,B0
  STAGE_A(0, 0, 0); STAGE_B(0, 0, 0); STAGE_A(1, 0, 0); STAGE_B(1, 0, 0);
  asm volatile("s_waitcnt vmcnt(4)" ::: "memory");
  BARRIER();

  for (int t = 0; t < NTt-1; ++t){
    const int b = t & 1, nb = b ^ 1;
    // ---- P0: needs A-half0(t), B-half0(t)
    #pragma unroll
    for (int q=0;q<4;++q){ aF[q][0]=RDA(b,q,0); aF[q][1]=RDA(b,q,1); }
    #pragma unroll
    for (int r=0;r<2;++r){ bF[r][0]=RDB(b,r,0); bF[r][1]=RDB(b,r,1); }
    STAGE_A(0, t+1, nb);
    __builtin_amdgcn_s_setprio(1);
    MM(0,0); MM(0,1); MM(1,0); MM(1,1); MM(2,0); MM(2,1); MM(3,0); MM(3,1);
    __builtin_amdgcn_s_setprio(0);
    asm volatile("s_waitcnt vmcnt(4)" ::: "memory");   // ensures A-half1(t)
    BARRIER();
    // ---- P1: needs A-half1(t)
    #pragma unroll
    for (int q=4;q<8;++q){ aF[q][0]=RDA(b,q,0); aF[q][1]=RDA(b,q,1); }
    STAGE_B(0, t+1, nb);
    __builtin_amdgcn_s_setprio(1);
    MM(4,0); MM(4,1); MM(5,0); MM(5,1); MM(6,0); MM(6,1); MM(7,0); MM(7,1);
    __builtin_amdgcn_s_setprio(0);
    asm volatile("s_waitcnt vmcnt(4)" ::: "memory");   // ensures B-half1(t)
    BARRIER();
    // ---- P2: needs B-half1(t)
    #pragma unroll
    for (int r=2;r<4;++r){ bF[r][0]=RDB(b,r,0); bF[r][1]=RDB(b,r,1); }
    STAGE_A(1, t+1, nb);
    __builtin_amdgcn_s_setprio(1);
    MM(0,2); MM(0,3); MM(1,2); MM(1,3); MM(2,2); MM(2,3); MM(3,2); MM(3,3);
    __builtin_amdgcn_s_setprio(0);
    BARRIER();
    // ---- P3
    STAGE_B(1, t+1, nb);
    __builtin_amdgcn_s_setprio(1);
    MM(4,2); MM(4,3); MM(5,2); MM(5,3); MM(6,2); MM(6,3); MM(7,2); MM(7,3);
    __builtin_amdgcn_s_setprio(0);
    asm volatile("s_waitcnt lgkmcnt(0)" ::: "memory"); // all reads of buf b done before t+1 stages into it
    asm volatile("s_waitcnt vmcnt(4)" ::: "memory");   // ensures A-half0,B-half0(t+1)
    BARRIER();
  }

  // ---- peeled last tile (no staging)
  {
    const int b = (NTt-1) & 1;
    #pragma unroll
    for (int q=0;q<4;++q){ aF[q][0]=RDA(b,q,0); aF[q][1]=RDA(b,q,1); }
    #pragma unroll
    for (int r=0;r<2;++r){ bF[r][0]=RDB(b,r,0); bF[r][1]=RDB(b,r,1); }
    __builtin_amdgcn_s_setprio(1);
    MM(0,0); MM(0,1); MM(1,0); MM(1,1); MM(2,0); MM(2,1); MM(3,0); MM(3,1);
    __builtin_amdgcn_s_setprio(0);
    asm volatile("s_waitcnt vmcnt(2)" ::: "memory");   // ensures A-half1
    BARRIER();
    #pragma unroll
    for (int q=4;q<8;++q){ aF[q][0]=RDA(b,q,0); aF[q][1]=RDA(b,q,1); }
    __builtin_amdgcn_s_setprio(1);
    MM(4,0); MM(4,1); MM(5,0); MM(5,1); MM(6,0); MM(6,1); MM(7,0); MM(7,1);
    __builtin_amdgcn_s_setprio(0);
    asm volatile("s_waitcnt vmcnt(0)" ::: "memory");   // ensures B-half1
    BARRIER();
    #pragma unroll
    for (int r=2;r<4;++r){ bF[r][0]=RDB(b,r,0); bF[r][1]=RDB(b,r,1); }
    MM(0,2); MM(0,3); MM(1,2); MM(1,3); MM(2,2); MM(2,3); MM(3,2); MM(3,3);
    MM(4,2); MM(4,3); MM(5,2); MM(5,3); MM(6,2); MM(6,3); MM(7,2); MM(7,3);
  }

  // ---- epilogue: LoRA add (h, B0 from global; L2-resident) + bf16 store
  float b0v[4][8];
  #pragma unroll
  for (int r=0;r<4;++r){
    int col = n0 + r*64 + wn*16 + (lane&15);
    const float4* bp = (const float4*)&B0[(size_t)col*8];
    float4 u0 = bp[0], u1 = bp[1];
    b0v[r][0]=u0.x; b0v[r][1]=u0.y; b0v[r][2]=u0.z; b0v[r][3]=u0.w;
    b0v[r][4]=u1.x; b0v[r][5]=u1.y; b0v[r][6]=u1.z; b0v[r][7]=u1.w;
  }
  #pragma unroll
  for (int q=0;q<8;++q){
    #pragma unroll
    for (int jj=0;jj<4;++jj){
      int row = m0 + q*32 + wm*16 + (lane>>4)*4 + jj;
      const float4* hp = (const float4*)&hmat[(size_t)row*8];
      float4 h0 = hp[0], h1 = hp[1];
      #pragma unroll
      for (int r=0;r<4;++r){
        float lor = h0.x*b0v[r][0]+h0.y*b0v[r][1]+h0.z*b0v[r][2]+h0.w*b0v[r][3]
                  + h1.x*b0v[r][4]+h1.y*b0v[r][5]+h1.z*b0v[r][6]+h1.w*b0v[r][7];
        int col = n0 + r*64 + wn*16 + (lane&15);
        C[(size_t)row*N + col] = f2bf(acc[q][r][jj] + 0.125f*lor);
      }
    }
  }
  #undef STAGE_A
  #undef STAGE_B
  #undef RDA
  #undef RDB
  #undef MM
  #undef BARRIER
}

// ---------------------------------------------------------------- 128x128 GEMM + LoRA (f32 out, out-proj)
template<int MODE>
__global__ __launch_bounds__(256) void gemm_lora(const ushort_t* __restrict__ A,
                                                 const ushort_t* __restrict__ Bw,
                                                 const float* __restrict__ hmat,
                                                 const float* __restrict__ B0,
                                                 void* __restrict__ C,
                                                 int M, int N, int K){
  __shared__ __align__(16) ushort_t As[128*32];
  __shared__ __align__(16) ushort_t Bs[128*32];
  __shared__ float hs[128][8];
  __shared__ float b0s[128][8];

  const int tid = threadIdx.x, lane = tid & 63, w = tid >> 6;
  const int wr = w >> 1, wc = w & 1;
  const int m0 = blockIdx.y*128, n0 = blockIdx.x*128;

  for (int i = tid; i < 128*8; i += 256) hs[i>>3][i&7]  = hmat[(size_t)(m0 + (i>>3))*8 + (i&7)];
  for (int i = tid; i < 128*8; i += 256) b0s[i>>3][i&7] = B0[(size_t)(n0 + (i>>3))*8 + (i&7)];

  f32x4 acc[4][4] = {};

  for (int k0 = 0; k0 < K; k0 += 32){
    __syncthreads();
    #pragma unroll
    for (int i=0;i<2;++i){
      int c = (w*2+i)*64 + lane;
      const ushort_t* ga = A  + (size_t)(m0 + (c>>2))*K + k0 + (c&3)*8;
      __builtin_amdgcn_global_load_lds(AS1(ga), AS3(As + (w*2+i)*512), 16, 0, 0);
      const ushort_t* gb = Bw + (size_t)(n0 + (c>>2))*K + k0 + (c&3)*8;
      __builtin_amdgcn_global_load_lds(AS1(gb), AS3(Bs + (w*2+i)*512), 16, 0, 0);
    }
    __syncthreads();
    short8 af[4], bf[4];
    #pragma unroll
    for (int m=0;m<4;++m) af[m] = *(const short8*)&As[(wr*64 + m*16 + (lane&15))*32 + (lane>>4)*8];
    #pragma unroll
    for (int n=0;n<4;++n) bf[n] = *(const short8*)&Bs[(wc*64 + n*16 + (lane&15))*32 + (lane>>4)*8];
    #pragma unroll
    for (int m=0;m<4;++m)
      #pragma unroll
      for (int n=0;n<4;++n)
        acc[m][n] = __builtin_amdgcn_mfma_f32_16x16x32_bf16(af[m], bf[n], acc[m][n], 0, 0, 0);
  }

  float b0r[4][8];
  #pragma unroll
  for (int n=0;n<4;++n){
    int cl = wc*64 + n*16 + (lane&15);
    #pragma unroll
    for (int r=0;r<8;++r) b0r[n][r] = b0s[cl][r];
  }
  #pragma unroll
  for (int m=0;m<4;++m){
    #pragma unroll
    for (int j=0;j<4;++j){
      int rl = wr*64 + m*16 + (lane>>4)*4 + j;
      float hr[8];
      #pragma unroll
      for (int r=0;r<8;++r) hr[r] = hs[rl][r];
      #pragma unroll
      for (int n=0;n<4;++n){
        int cl = wc*64 + n*16 + (lane&15);
        float lor = 0.f;
        #pragma unroll
        for (int r=0;r<8;++r) lor += hr[r]*b0r[n][r];
        float v = acc[m][n][j] + 0.125f*lor;
        size_t idx = (size_t)(m0+rl)*N + (n0+cl);
        if (MODE==0) ((ushort_t*)C)[idx] = f2bf(v);
        else         ((float*)C)[idx]    = v;
      }
    }
  }
}

// ---------------------------------------------------------------- RoPE (in place on qkv bf16)
__global__ __launch_bounds__(256) void rope_kernel(ushort_t* __restrict__ qkv,
                                                   const float* __restrict__ cosb,
                                                   const float* __restrict__ sinb){
  int idx = blockIdx.x*256 + threadIdx.x;   // 0 .. 1048575
  int d = idx & 7;
  int g = idx >> 3;
  int h_ = g & 15;
  int s  = (g>>4) & 1;
  int t  = (g>>5) & 511;
  int b  = g >> 14;
  size_t base = (size_t)(b*512 + t)*6144 + s*2048 + h_*128;
  float x1 = bf2f(qkv[base+d]), x2 = bf2f(qkv[base+d+8]);
  float c = cosb[t*8+d], sn = sinb[t*8+d];
  qkv[base+d]   = f2bf(x1*c - x2*sn);
  qkv[base+d+8] = f2bf(x2*c + x1*sn);
}

// ---------------------------------------------------------------- flash attention
__global__ __launch_bounds__(256) void attn_kernel(const ushort_t* __restrict__ qkv,
                                                   ushort_t* __restrict__ y){
  __shared__ __align__(16) ushort_t Ks[32*128];
  __shared__ __align__(16) ushort_t Vt[128*32];
  __shared__ __align__(16) ushort_t Pl[4][16][32];

  const int qt = blockIdx.x, hh = blockIdx.y, b = blockIdx.z;
  const int tid = threadIdx.x, lane = tid & 63, w = tid >> 6;
  const int qb0 = qt*64;
  const int row_base = b*512;
  const int qoff = hh*128;
  const int koff = 2048 + hh*128;
  const int voff = 4096 + hh*128;
  const float scale = 0.08838834764831845f;

  short8 qf[4];
  {
    int qr = qb0 + w*16 + (lane & 15);
    const ushort_t* qp = qkv + (size_t)(row_base + qr)*6144 + qoff + (lane>>4)*8;
    #pragma unroll
    for (int kc=0;kc<4;++kc) qf[kc] = *(const short8*)(qp + kc*32);
  }

  f32x4 o[8] = {};
  float mrow[4] = {-1e30f,-1e30f,-1e30f,-1e30f};
  float lrow[4] = {0,0,0,0};

  const int ntiles = qb0/32 + 2;
  const int wmax = qb0 + w*16 + 15;

  for (int t = 0; t < ntiles; ++t){
    int kv0 = t*32;
    __syncthreads();
    #pragma unroll
    for (int i=0;i<2;++i){
      int c = (w*2+i)*64 + lane;
      const ushort_t* g = qkv + (size_t)(row_base + kv0 + (c>>4))*6144 + koff + (c&15)*8;
      __builtin_amdgcn_global_load_lds(AS1(g), AS3(Ks + (w*2+i)*512), 16, 0, 0);
    }
    {
      int r = tid >> 3, d0 = (tid & 7)*16;
      const ushort_t* g = qkv + (size_t)(row_base + kv0 + r)*6144 + voff + d0;
      short8 v0 = *(const short8*)g;
      short8 v1 = *(const short8*)(g + 8);
      #pragma unroll
      for (int ii=0; ii<8; ++ii) Vt[(d0+ii)*32 + r]   = (ushort_t)v0[ii];
      #pragma unroll
      for (int ii=0; ii<8; ++ii) Vt[(d0+8+ii)*32 + r] = (ushort_t)v1[ii];
    }
    __syncthreads();
    if (kv0 > wmax) continue;

    f32x4 s[2] = {};
    #pragma unroll
    for (int cg=0;cg<2;++cg)
      #pragma unroll
      for (int kc=0;kc<4;++kc){
        short8 kf = *(const short8*)&Ks[(cg*16 + (lane&15))*128 + kc*32 + (lane>>4)*8];
        s[cg] = __builtin_amdgcn_mfma_f32_16x16x32_bf16(qf[kc], kf, s[cg], 0, 0, 0);
      }

    float fac[4], p0[4], p1[4];
    #pragma unroll
    for (int j=0;j<4;++j){
      int qr = qb0 + w*16 + (lane>>4)*4 + j;
      float a0 = s[0][j]*scale; if (kv0 + (lane&15) > qr)      a0 = -1e30f;
      float a1 = s[1][j]*scale; if (kv0 + 16 + (lane&15) > qr) a1 = -1e30f;
      float mx = fmaxf(a0, a1);
      for (int d=1; d<16; d<<=1) mx = fmaxf(mx, __shfl_xor(mx, d, 16));
      float mn = fmaxf(mrow[j], mx);
      float f  = __expf(mrow[j] - mn);
      mrow[j] = mn;
      p0[j] = __expf(a0 - mn);
      p1[j] = __expf(a1 - mn);
      float rs = p0[j] + p1[j];
      for (int d=1; d<16; d<<=1) rs += __shfl_xor(rs, d, 16);
      lrow[j] = lrow[j]*f + rs;
      fac[j] = f;
    }
    #pragma unroll
    for (int n=0;n<8;++n){
      #pragma unroll
      for (int j=0;j<4;++j) o[n][j] *= fac[j];
    }
    #pragma unroll
    for (int j=0;j<4;++j){
      Pl[w][(lane>>4)*4+j][(lane&15)]      = f2bf(p0[j]);
      Pl[w][(lane>>4)*4+j][16+(lane&15)]   = f2bf(p1[j]);
    }
    short8 pf = *(const short8*)&Pl[w][lane&15][(lane>>4)*8];
    #pragma unroll
    for (int n=0;n<8;++n){
      short8 vf = *(const short8*)&Vt[(n*16 + (lane&15))*32 + (lane>>4)*8];
      o[n] = __builtin_amdgcn_mfma_f32_16x16x32_bf16(pf, vf, o[n], 0, 0, 0);
    }
  }

  #pragma unroll
  for (int j=0;j<4;++j){
    float inv = 1.0f / lrow[j];
    int qr = qb0 + w*16 + (lane>>4)*4 + j;
    #pragma unroll
    for (int n=0;n<8;++n)
      y[(size_t)(row_base+qr)*2048 + hh*128 + n*16 + (lane&15)] = f2bf(o[n][j]*inv);
  }
}

// ---------------------------------------------------------------- launch
extern "C" void kernel_launch(void* const* d_in, const int* in_sizes, int n_in,
                              void* d_out, int out_size, void* d_ws, size_t ws_size,
                              hipStream_t stream){
  const float* x       = (const float*)d_in[0];
  const float* Wqkv    = (const float*)d_in[1];
  const float* A0_qkv  = (const float*)d_in[2];
  const float* B0_qkv  = (const float*)d_in[3];
  const float* da_qkv  = (const float*)d_in[4];
  const float* db_qkv  = (const float*)d_in[5];
  const float* Wout    = (const float*)d_in[6];
  const float* A0_out  = (const float*)d_in[7];
  const float* B0_out  = (const float*)d_in[8];
  const float* da_out  = (const float*)d_in[9];
  const float* db_out  = (const float*)d_in[10];
  const float* cosb    = (const float*)d_in[11];
  const float* sinb    = (const float*)d_in[12];
  float* out = (float*)d_out;

  char* ws = (char*)d_ws;
  ushort_t* x_bf    = (ushort_t*)(ws);
  ushort_t* wqkv_bf = (ushort_t*)(ws + 16777216);
  ushort_t* wout_bf = (ushort_t*)(ws + 41943040);
  ushort_t* qkv_bf  = (ushort_t*)(ws + 50331648);
  ushort_t* y_bf    = (ushort_t*)(ws + 100663296);
  float*    h_qkv   = (float*)   (ws + 117440512);
  float*    h_out   = (float*)   (ws + 117571584);

  const int M = 4096;
  const int C = 2048;
  const int N3 = 6144;

  conv_f2b<<<8192, 256, 0, stream>>>(x,    x_bf,    M*C);
  conv_f2b<<<12288,256, 0, stream>>>(Wqkv, wqkv_bf, N3*C);
  conv_f2b<<<4096, 256, 0, stream>>>(Wout, wout_bf, C*C);

  lora_h<false><<<M, 256, 0, stream>>>(x, A0_qkv, da_qkv, db_qkv, h_qkv, C);

  gemm256_lora<<<(M/256)*(N3/256), 512, 0, stream>>>(x_bf, wqkv_bf, h_qkv, B0_qkv,
                                                     qkv_bf, M, N3, C);

  rope_kernel<<<4096, 256, 0, stream>>>(qkv_bf, cosb, sinb);

  attn_kernel<<<dim3(8, 16, 8), 256, 0, stream>>>(qkv_bf, y_bf);

  lora_h<true><<<M, 256, 0, stream>>>(y_bf, A0_out, da_out, db_out, h_out, C);

  gemm_lora<1><<<dim3(C/128, M/128), 256, 0, stream>>>(y_bf, wout_bf, h_out, B0_out,
                                                       out, M, C, C);
}

// Round 7
// 311.227 us; speedup vs baseline: 1.2335x; 1.0667x over previous
//
#include <hip/hip_runtime.h>

typedef unsigned short ushort_t;
typedef __attribute__((ext_vector_type(8))) short short8;
typedef __attribute__((ext_vector_type(4))) float f32x4;

#define AS1(p) ((const __attribute__((address_space(1))) void*)(p))
#define AS3(p) ((__attribute__((address_space(3))) void*)(p))

__device__ __forceinline__ ushort_t f2bf(float f){
  unsigned u = __float_as_uint(f);
  u += 0x7FFFu + ((u>>16)&1u);
  return (ushort_t)(u>>16);
}
__device__ __forceinline__ float bf2f(ushort_t h){
  return __uint_as_float(((unsigned)h)<<16);
}

// ---------------------------------------------------------------- conv fp32->bf16
__global__ __launch_bounds__(256) void conv_f2b(const float* __restrict__ src,
                                                ushort_t* __restrict__ dst, int n){
  int i = (blockIdx.x*256 + threadIdx.x)*4;
  if (i < n){
    float4 v = *(const float4*)&src[i];
    ushort_t o0=f2bf(v.x), o1=f2bf(v.y), o2=f2bf(v.z), o3=f2bf(v.w);
    ushort4 o; o.x=o0; o.y=o1; o.z=o2; o.w=o3;
    *(ushort4*)&dst[i] = o;
  }
}

// ---------------------------------------------------------------- LoRA h = X @ A0^T * (da*db)
template<bool BF16IN>
__global__ __launch_bounds__(256) void lora_h(const void* __restrict__ X,
                                              const float* __restrict__ A0,
                                              const float* __restrict__ da,
                                              const float* __restrict__ db,
                                              float* __restrict__ out, int K){
  int m = blockIdx.x;
  int tid = threadIdx.x, lane = tid & 63, w = tid >> 6;
  float part[8] = {0,0,0,0,0,0,0,0};
  for (int k = tid; k < K; k += 256){
    float xv;
    if (BF16IN) xv = bf2f(((const ushort_t*)X)[(size_t)m*K + k]);
    else        xv = ((const float*)X)[(size_t)m*K + k];
    #pragma unroll
    for (int r=0;r<8;++r) part[r] += xv * A0[r*K + k];
  }
  #pragma unroll
  for (int r=0;r<8;++r)
    for (int d=1;d<64;d<<=1) part[r] += __shfl_xor(part[r], d, 64);
  __shared__ float wsum[4][8];
  if (lane==0){
    #pragma unroll
    for (int r=0;r<8;++r) wsum[w][r] = part[r];
  }
  __syncthreads();
  if (tid < 8){
    float s = wsum[0][tid]+wsum[1][tid]+wsum[2][tid]+wsum[3][tid];
    out[(size_t)m*8 + tid] = s * da[tid]*db[tid];
  }
}

// ---------------------------------------------------------------- 128x256 2-phase/K-tile GEMM + LoRA
// C[m,n] = sum_k A[m,k]*Bw[n,k] + 0.125 * sum_r h[m,r]*B0[n,r]
// 512 threads = 8 waves (2M x 4N); wave (wm,wn) owns 64x64: rows q*32+wm*16 (q0-3), cols r*64+wn*16 (r0-3).
// BK=64; LDS 96KB double-buffered: A 2x16KB, B 2x32KB. Stage unit = 8KB = 64 rows.
// Per tile: P0 {read A(all)+B(r0-1); stage A0,A1,B0,B1(t+1); 16 MFMA; vmcnt(4)}
//           P1 {read B(r2-3);        stage B2,B3(t+1);      16 MFMA; lgkm(0); vmcnt(2)}
// MODE 0: bf16 out ; MODE 1: f32 out
template<int MODE>
__global__ __launch_bounds__(512, 1) void gemm128x256_lora(
    const ushort_t* __restrict__ A, const ushort_t* __restrict__ Bw,
    const float* __restrict__ hmat, const float* __restrict__ B0,
    void* __restrict__ C, int M, int N, int K)
{
  __shared__ __align__(16) char smem[98304];   // A: [0,32768) ; B: [32768, 98304)
  const int tid = threadIdx.x, lane = tid & 63, w = tid >> 6;
  const int wm = w >> 2, wn = w & 3;

  // XCD-aware bijective swizzle (grid % 8 == 0 for both call sites)
  const int nbn = N >> 8;
  const int nwg = (M >> 7) * nbn;
  const int q8 = nwg >> 3;
  const int swz = ((int)blockIdx.x & 7)*q8 + ((int)blockIdx.x >> 3);
  const int m0 = (swz / nbn) << 7, n0 = (swz % nbn) << 8;

  const int NTt = K >> 6;

  // stage geometry: one global_load_lds per unit (512 lanes x 16B = 8KB = 64 rows x 64 cols bf16)
  const int srow8  = tid >> 3;                      // row within unit
  const int schunk = (lane & 7) ^ (lane >> 3);      // pre-swizzled source chunk (row&7 == lane>>3)

  #define STAGE_AU(u, tt, bb) do { \
    const ushort_t* g_ = A + (size_t)(m0 + (u)*64 + srow8)*K + (tt)*64 + schunk*8; \
    __builtin_amdgcn_global_load_lds(AS1(g_), AS3(smem + (bb)*16384 + (u)*8192 + w*1024), 16, 0, 0); \
  } while(0)
  #define STAGE_BU(u, tt, bb) do { \
    const ushort_t* g_ = Bw + (size_t)(n0 + (u)*64 + srow8)*K + (tt)*64 + schunk*8; \
    __builtin_amdgcn_global_load_lds(AS1(g_), AS3(smem + 32768 + (bb)*32768 + (u)*8192 + w*1024), 16, 0, 0); \
  } while(0)

  // swizzled reads: LDS[row][c] = G[row][c ^ (row&7)]; row&7 == lane&7 for all fragments
  #define RDA(bb, q, kk) (*(const short8*)(smem + (bb)*16384 + \
      ((q)*32 + wm*16 + (lane&15))*128 + ((((kk)*4 + (lane>>4)) ^ (lane&7))<<4)))
  #define RDB(bb, rg, kk) (*(const short8*)(smem + 32768 + (bb)*32768 + \
      ((rg)*64 + wn*16 + (lane&15))*128 + ((((kk)*4 + (lane>>4)) ^ (lane&7))<<4)))

  #define MM0(q,rl) do{ \
    acc[q][rl] = __builtin_amdgcn_mfma_f32_16x16x32_bf16(aF[q][0], bF[rl][0], acc[q][rl], 0,0,0); \
    acc[q][rl] = __builtin_amdgcn_mfma_f32_16x16x32_bf16(aF[q][1], bF[rl][1], acc[q][rl], 0,0,0); \
  }while(0)
  #define MM1(q,rl) do{ \
    acc[q][(rl)+2] = __builtin_amdgcn_mfma_f32_16x16x32_bf16(aF[q][0], bF[rl][0], acc[q][(rl)+2], 0,0,0); \
    acc[q][(rl)+2] = __builtin_amdgcn_mfma_f32_16x16x32_bf16(aF[q][1], bF[rl][1], acc[q][(rl)+2], 0,0,0); \
  }while(0)

  #define BARRIER() asm volatile("s_barrier" ::: "memory")

  short8 aF[4][2];
  short8 bF[2][2];
  f32x4 acc[4][4] = {};

  // prologue: stage tile 0 in steady-state FIFO order {A0,A1,B0,B1},{B2,B3}
  STAGE_AU(0,0,0); STAGE_AU(1,0,0); STAGE_BU(0,0,0); STAGE_BU(1,0,0);
  STAGE_BU(2,0,0); STAGE_BU(3,0,0);
  asm volatile("s_waitcnt vmcnt(2)" ::: "memory");
  BARRIER();

  for (int t = 0; t < NTt-1; ++t){
    const int b = t & 1, nb = b ^ 1;
    // ---- P0: needs A0,A1,B0,B1(t) (resident)
    #pragma unroll
    for (int q=0;q<4;++q){ aF[q][0]=RDA(b,q,0); aF[q][1]=RDA(b,q,1); }
    #pragma unroll
    for (int rl=0;rl<2;++rl){ bF[rl][0]=RDB(b,rl,0); bF[rl][1]=RDB(b,rl,1); }
    STAGE_AU(0,t+1,nb); STAGE_AU(1,t+1,nb); STAGE_BU(0,t+1,nb); STAGE_BU(1,t+1,nb);
    __builtin_amdgcn_s_setprio(1);
    MM0(0,0); MM0(0,1); MM0(1,0); MM0(1,1);
    MM0(2,0); MM0(2,1); MM0(3,0); MM0(3,1);
    __builtin_amdgcn_s_setprio(0);
    asm volatile("s_waitcnt vmcnt(4)" ::: "memory");   // drains B2,B3(t)
    BARRIER();
    // ---- P1: needs B2,B3(t)
    #pragma unroll
    for (int rl=0;rl<2;++rl){ bF[rl][0]=RDB(b,rl+2,0); bF[rl][1]=RDB(b,rl+2,1); }
    STAGE_BU(2,t+1,nb); STAGE_BU(3,t+1,nb);
    __builtin_amdgcn_s_setprio(1);
    MM1(0,0); MM1(0,1); MM1(1,0); MM1(1,1);
    MM1(2,0); MM1(2,1); MM1(3,0); MM1(3,1);
    __builtin_amdgcn_s_setprio(0);
    asm volatile("s_waitcnt lgkmcnt(0)" ::: "memory"); // buf b reads done before t+1 stages into it
    asm volatile("s_waitcnt vmcnt(2)" ::: "memory");   // drains A0,A1,B0,B1(t+1)
    BARRIER();
  }

  // ---- peeled last tile (no staging)
  {
    const int b = (NTt-1) & 1;
    #pragma unroll
    for (int q=0;q<4;++q){ aF[q][0]=RDA(b,q,0); aF[q][1]=RDA(b,q,1); }
    #pragma unroll
    for (int rl=0;rl<2;++rl){ bF[rl][0]=RDB(b,rl,0); bF[rl][1]=RDB(b,rl,1); }
    __builtin_amdgcn_s_setprio(1);
    MM0(0,0); MM0(0,1); MM0(1,0); MM0(1,1);
    MM0(2,0); MM0(2,1); MM0(3,0); MM0(3,1);
    __builtin_amdgcn_s_setprio(0);
    asm volatile("s_waitcnt vmcnt(0)" ::: "memory");   // drains B2,B3(last)
    BARRIER();
    #pragma unroll
    for (int rl=0;rl<2;++rl){ bF[rl][0]=RDB(b,rl+2,0); bF[rl][1]=RDB(b,rl+2,1); }
    MM1(0,0); MM1(0,1); MM1(1,0); MM1(1,1);
    MM1(2,0); MM1(2,1); MM1(3,0); MM1(3,1);
  }

  // ---- epilogue: LoRA add (h, B0 from global; L2-resident) + store
  float b0v[4][8];
  #pragma unroll
  for (int r=0;r<4;++r){
    int col = n0 + r*64 + wn*16 + (lane&15);
    const float4* bp = (const float4*)&B0[(size_t)col*8];
    float4 u0 = bp[0], u1 = bp[1];
    b0v[r][0]=u0.x; b0v[r][1]=u0.y; b0v[r][2]=u0.z; b0v[r][3]=u0.w;
    b0v[r][4]=u1.x; b0v[r][5]=u1.y; b0v[r][6]=u1.z; b0v[r][7]=u1.w;
  }
  #pragma unroll
  for (int q=0;q<4;++q){
    #pragma unroll
    for (int jj=0;jj<4;++jj){
      int row = m0 + q*32 + wm*16 + (lane>>4)*4 + jj;
      const float4* hp = (const float4*)&hmat[(size_t)row*8];
      float4 h0 = hp[0], h1 = hp[1];
      #pragma unroll
      for (int r=0;r<4;++r){
        float lor = h0.x*b0v[r][0]+h0.y*b0v[r][1]+h0.z*b0v[r][2]+h0.w*b0v[r][3]
                  + h1.x*b0v[r][4]+h1.y*b0v[r][5]+h1.z*b0v[r][6]+h1.w*b0v[r][7];
        int col = n0 + r*64 + wn*16 + (lane&15);
        float v = acc[q][r][jj] + 0.125f*lor;
        if (MODE==0) ((ushort_t*)C)[(size_t)row*N + col] = f2bf(v);
        else         ((float*)C)[(size_t)row*N + col]    = v;
      }
    }
  }
  #undef STAGE_AU
  #undef STAGE_BU
  #undef RDA
  #undef RDB
  #undef MM0
  #undef MM1
  #undef BARRIER
}

// ---------------------------------------------------------------- RoPE (in place on qkv bf16)
__global__ __launch_bounds__(256) void rope_kernel(ushort_t* __restrict__ qkv,
                                                   const float* __restrict__ cosb,
                                                   const float* __restrict__ sinb){
  int idx = blockIdx.x*256 + threadIdx.x;   // 0 .. 1048575
  int d = idx & 7;
  int g = idx >> 3;
  int h_ = g & 15;
  int s  = (g>>4) & 1;
  int t  = (g>>5) & 511;
  int b  = g >> 14;
  size_t base = (size_t)(b*512 + t)*6144 + s*2048 + h_*128;
  float x1 = bf2f(qkv[base+d]), x2 = bf2f(qkv[base+d+8]);
  float c = cosb[t*8+d], sn = sinb[t*8+d];
  qkv[base+d]   = f2bf(x1*c - x2*sn);
  qkv[base+d+8] = f2bf(x2*c + x1*sn);
}

// ---------------------------------------------------------------- flash attention
__global__ __launch_bounds__(256) void attn_kernel(const ushort_t* __restrict__ qkv,
                                                   ushort_t* __restrict__ y){
  __shared__ __align__(16) ushort_t Ks[32*128];
  __shared__ __align__(16) ushort_t Vt[128*32];
  __shared__ __align__(16) ushort_t Pl[4][16][32];

  const int qt = blockIdx.x, hh = blockIdx.y, b = blockIdx.z;
  const int tid = threadIdx.x, lane = tid & 63, w = tid >> 6;
  const int qb0 = qt*64;
  const int row_base = b*512;
  const int qoff = hh*128;
  const int koff = 2048 + hh*128;
  const int voff = 4096 + hh*128;
  const float scale = 0.08838834764831845f;

  short8 qf[4];
  {
    int qr = qb0 + w*16 + (lane & 15);
    const ushort_t* qp = qkv + (size_t)(row_base + qr)*6144 + qoff + (lane>>4)*8;
    #pragma unroll
    for (int kc=0;kc<4;++kc) qf[kc] = *(const short8*)(qp + kc*32);
  }

  f32x4 o[8] = {};
  float mrow[4] = {-1e30f,-1e30f,-1e30f,-1e30f};
  float lrow[4] = {0,0,0,0};

  const int ntiles = qb0/32 + 2;
  const int wmax = qb0 + w*16 + 15;

  for (int t = 0; t < ntiles; ++t){
    int kv0 = t*32;
    __syncthreads();
    #pragma unroll
    for (int i=0;i<2;++i){
      int c = (w*2+i)*64 + lane;
      const ushort_t* g = qkv + (size_t)(row_base + kv0 + (c>>4))*6144 + koff + (c&15)*8;
      __builtin_amdgcn_global_load_lds(AS1(g), AS3(Ks + (w*2+i)*512), 16, 0, 0);
    }
    {
      int r = tid >> 3, d0 = (tid & 7)*16;
      const ushort_t* g = qkv + (size_t)(row_base + kv0 + r)*6144 + voff + d0;
      short8 v0 = *(const short8*)g;
      short8 v1 = *(const short8*)(g + 8);
      #pragma unroll
      for (int ii=0; ii<8; ++ii) Vt[(d0+ii)*32 + r]   = (ushort_t)v0[ii];
      #pragma unroll
      for (int ii=0; ii<8; ++ii) Vt[(d0+8+ii)*32 + r] = (ushort_t)v1[ii];
    }
    __syncthreads();
    if (kv0 > wmax) continue;

    f32x4 s[2] = {};
    #pragma unroll
    for (int cg=0;cg<2;++cg)
      #pragma unroll
      for (int kc=0;kc<4;++kc){
        short8 kf = *(const short8*)&Ks[(cg*16 + (lane&15))*128 + kc*32 + (lane>>4)*8];
        s[cg] = __builtin_amdgcn_mfma_f32_16x16x32_bf16(qf[kc], kf, s[cg], 0, 0, 0);
      }

    float fac[4], p0[4], p1[4];
    #pragma unroll
    for (int j=0;j<4;++j){
      int qr = qb0 + w*16 + (lane>>4)*4 + j;
      float a0 = s[0][j]*scale; if (kv0 + (lane&15) > qr)      a0 = -1e30f;
      float a1 = s[1][j]*scale; if (kv0 + 16 + (lane&15) > qr) a1 = -1e30f;
      float mx = fmaxf(a0, a1);
      for (int d=1; d<16; d<<=1) mx = fmaxf(mx, __shfl_xor(mx, d, 16));
      float mn = fmaxf(mrow[j], mx);
      float f  = __expf(mrow[j] - mn);
      mrow[j] = mn;
      p0[j] = __expf(a0 - mn);
      p1[j] = __expf(a1 - mn);
      float rs = p0[j] + p1[j];
      for (int d=1; d<16; d<<=1) rs += __shfl_xor(rs, d, 16);
      lrow[j] = lrow[j]*f + rs;
      fac[j] = f;
    }
    #pragma unroll
    for (int n=0;n<8;++n){
      #pragma unroll
      for (int j=0;j<4;++j) o[n][j] *= fac[j];
    }
    #pragma unroll
    for (int j=0;j<4;++j){
      Pl[w][(lane>>4)*4+j][(lane&15)]      = f2bf(p0[j]);
      Pl[w][(lane>>4)*4+j][16+(lane&15)]   = f2bf(p1[j]);
    }
    short8 pf = *(const short8*)&Pl[w][lane&15][(lane>>4)*8];
    #pragma unroll
    for (int n=0;n<8;++n){
      short8 vf = *(const short8*)&Vt[(n*16 + (lane&15))*32 + (lane>>4)*8];
      o[n] = __builtin_amdgcn_mfma_f32_16x16x32_bf16(pf, vf, o[n], 0, 0, 0);
    }
  }

  #pragma unroll
  for (int j=0;j<4;++j){
    float inv = 1.0f / lrow[j];
    int qr = qb0 + w*16 + (lane>>4)*4 + j;
    #pragma unroll
    for (int n=0;n<8;++n)
      y[(size_t)(row_base+qr)*2048 + hh*128 + n*16 + (lane&15)] = f2bf(o[n][j]*inv);
  }
}

// ---------------------------------------------------------------- launch
extern "C" void kernel_launch(void* const* d_in, const int* in_sizes, int n_in,
                              void* d_out, int out_size, void* d_ws, size_t ws_size,
                              hipStream_t stream){
  const float* x       = (const float*)d_in[0];
  const float* Wqkv    = (const float*)d_in[1];
  const float* A0_qkv  = (const float*)d_in[2];
  const float* B0_qkv  = (const float*)d_in[3];
  const float* da_qkv  = (const float*)d_in[4];
  const float* db_qkv  = (const float*)d_in[5];
  const float* Wout    = (const float*)d_in[6];
  const float* A0_out  = (const float*)d_in[7];
  const float* B0_out  = (const float*)d_in[8];
  const float* da_out  = (const float*)d_in[9];
  const float* db_out  = (const float*)d_in[10];
  const float* cosb    = (const float*)d_in[11];
  const float* sinb    = (const float*)d_in[12];
  float* out = (float*)d_out;

  char* ws = (char*)d_ws;
  ushort_t* x_bf    = (ushort_t*)(ws);
  ushort_t* wqkv_bf = (ushort_t*)(ws + 16777216);
  ushort_t* wout_bf = (ushort_t*)(ws + 41943040);
  ushort_t* qkv_bf  = (ushort_t*)(ws + 50331648);
  ushort_t* y_bf    = (ushort_t*)(ws + 100663296);
  float*    h_qkv   = (float*)   (ws + 117440512);
  float*    h_out   = (float*)   (ws + 117571584);

  const int M = 4096;
  const int C = 2048;
  const int N3 = 6144;

  conv_f2b<<<8192, 256, 0, stream>>>(x,    x_bf,    M*C);
  conv_f2b<<<12288,256, 0, stream>>>(Wqkv, wqkv_bf, N3*C);
  conv_f2b<<<4096, 256, 0, stream>>>(Wout, wout_bf, C*C);

  lora_h<false><<<M, 256, 0, stream>>>(x, A0_qkv, da_qkv, db_qkv, h_qkv, C);

  gemm128x256_lora<0><<<(M/128)*(N3/256), 512, 0, stream>>>(x_bf, wqkv_bf, h_qkv, B0_qkv,
                                                            qkv_bf, M, N3, C);

  rope_kernel<<<4096, 256, 0, stream>>>(qkv_bf, cosb, sinb);

  attn_kernel<<<dim3(8, 16, 8), 256, 0, stream>>>(qkv_bf, y_bf);

  lora_h<true><<<M, 256, 0, stream>>>(y_bf, A0_out, da_out, db_out, h_out, C);

  gemm128x256_lora<1><<<(M/128)*(C/256), 512, 0, stream>>>(y_bf, wout_bf, h_out, B0_out,
                                                           out, M, C, C);
}

// Round 8
// 272.171 us; speedup vs baseline: 1.4105x; 1.1435x over previous
//
#include <hip/hip_runtime.h>

typedef unsigned short ushort_t;
typedef __attribute__((ext_vector_type(8))) short short8;
typedef __attribute__((ext_vector_type(4))) float f32x4;

#define AS1(p) ((const __attribute__((address_space(1))) void*)(p))
#define AS3(p) ((__attribute__((address_space(3))) void*)(p))

__device__ __forceinline__ ushort_t f2bf(float f){
  unsigned u = __float_as_uint(f);
  u += 0x7FFFu + ((u>>16)&1u);
  return (ushort_t)(u>>16);
}
__device__ __forceinline__ float bf2f(ushort_t h){
  return __uint_as_float(((unsigned)h)<<16);
}

// ---------------------------------------------------------------- conv fp32->bf16
__global__ __launch_bounds__(256) void conv_f2b(const float* __restrict__ src,
                                                ushort_t* __restrict__ dst, int n){
  int i = (blockIdx.x*256 + threadIdx.x)*4;
  if (i < n){
    float4 v = *(const float4*)&src[i];
    ushort_t o0=f2bf(v.x), o1=f2bf(v.y), o2=f2bf(v.z), o3=f2bf(v.w);
    ushort4 o; o.x=o0; o.y=o1; o.z=o2; o.w=o3;
    *(ushort4*)&dst[i] = o;
  }
}

// ---------------------------------------------------------------- LoRA h = X @ A0^T * (da*db)
template<bool BF16IN>
__global__ __launch_bounds__(256) void lora_h(const void* __restrict__ X,
                                              const float* __restrict__ A0,
                                              const float* __restrict__ da,
                                              const float* __restrict__ db,
                                              float* __restrict__ out, int K){
  int m = blockIdx.x;
  int tid = threadIdx.x, lane = tid & 63, w = tid >> 6;
  float part[8] = {0,0,0,0,0,0,0,0};
  for (int k = tid; k < K; k += 256){
    float xv;
    if (BF16IN) xv = bf2f(((const ushort_t*)X)[(size_t)m*K + k]);
    else        xv = ((const float*)X)[(size_t)m*K + k];
    #pragma unroll
    for (int r=0;r<8;++r) part[r] += xv * A0[r*K + k];
  }
  #pragma unroll
  for (int r=0;r<8;++r)
    for (int d=1;d<64;d<<=1) part[r] += __shfl_xor(part[r], d, 64);
  __shared__ float wsum[4][8];
  if (lane==0){
    #pragma unroll
    for (int r=0;r<8;++r) wsum[w][r] = part[r];
  }
  __syncthreads();
  if (tid < 8){
    float s = wsum[0][tid]+wsum[1][tid]+wsum[2][tid]+wsum[3][tid];
    out[(size_t)m*8 + tid] = s * da[tid]*db[tid];
  }
}

// ---------------------------------------------------------------- 128x256 2-phase/K-tile GEMM + LoRA
template<int MODE>
__global__ __launch_bounds__(512, 1) void gemm128x256_lora(
    const ushort_t* __restrict__ A, const ushort_t* __restrict__ Bw,
    const float* __restrict__ hmat, const float* __restrict__ B0,
    void* __restrict__ C, int M, int N, int K)
{
  __shared__ __align__(16) char smem[98304];   // A: [0,32768) ; B: [32768, 98304)
  const int tid = threadIdx.x, lane = tid & 63, w = tid >> 6;
  const int wm = w >> 2, wn = w & 3;

  const int nbn = N >> 8;
  const int nwg = (M >> 7) * nbn;
  const int q8 = nwg >> 3;
  const int swz = ((int)blockIdx.x & 7)*q8 + ((int)blockIdx.x >> 3);
  const int m0 = (swz / nbn) << 7, n0 = (swz % nbn) << 8;

  const int NTt = K >> 6;

  const int srow8  = tid >> 3;
  const int schunk = (lane & 7) ^ (lane >> 3);

  #define STAGE_AU(u, tt, bb) do { \
    const ushort_t* g_ = A + (size_t)(m0 + (u)*64 + srow8)*K + (tt)*64 + schunk*8; \
    __builtin_amdgcn_global_load_lds(AS1(g_), AS3(smem + (bb)*16384 + (u)*8192 + w*1024), 16, 0, 0); \
  } while(0)
  #define STAGE_BU(u, tt, bb) do { \
    const ushort_t* g_ = Bw + (size_t)(n0 + (u)*64 + srow8)*K + (tt)*64 + schunk*8; \
    __builtin_amdgcn_global_load_lds(AS1(g_), AS3(smem + 32768 + (bb)*32768 + (u)*8192 + w*1024), 16, 0, 0); \
  } while(0)

  #define RDA(bb, q, kk) (*(const short8*)(smem + (bb)*16384 + \
      ((q)*32 + wm*16 + (lane&15))*128 + ((((kk)*4 + (lane>>4)) ^ (lane&7))<<4)))
  #define RDB(bb, rg, kk) (*(const short8*)(smem + 32768 + (bb)*32768 + \
      ((rg)*64 + wn*16 + (lane&15))*128 + ((((kk)*4 + (lane>>4)) ^ (lane&7))<<4)))

  #define MM0(q,rl) do{ \
    acc[q][rl] = __builtin_amdgcn_mfma_f32_16x16x32_bf16(aF[q][0], bF[rl][0], acc[q][rl], 0,0,0); \
    acc[q][rl] = __builtin_amdgcn_mfma_f32_16x16x32_bf16(aF[q][1], bF[rl][1], acc[q][rl], 0,0,0); \
  }while(0)
  #define MM1(q,rl) do{ \
    acc[q][(rl)+2] = __builtin_amdgcn_mfma_f32_16x16x32_bf16(aF[q][0], bF[rl][0], acc[q][(rl)+2], 0,0,0); \
    acc[q][(rl)+2] = __builtin_amdgcn_mfma_f32_16x16x32_bf16(aF[q][1], bF[rl][1], acc[q][(rl)+2], 0,0,0); \
  }while(0)

  #define BARRIER() asm volatile("s_barrier" ::: "memory")

  short8 aF[4][2];
  short8 bF[2][2];
  f32x4 acc[4][4] = {};

  STAGE_AU(0,0,0); STAGE_AU(1,0,0); STAGE_BU(0,0,0); STAGE_BU(1,0,0);
  STAGE_BU(2,0,0); STAGE_BU(3,0,0);
  asm volatile("s_waitcnt vmcnt(2)" ::: "memory");
  BARRIER();

  for (int t = 0; t < NTt-1; ++t){
    const int b = t & 1, nb = b ^ 1;
    #pragma unroll
    for (int q=0;q<4;++q){ aF[q][0]=RDA(b,q,0); aF[q][1]=RDA(b,q,1); }
    #pragma unroll
    for (int rl=0;rl<2;++rl){ bF[rl][0]=RDB(b,rl,0); bF[rl][1]=RDB(b,rl,1); }
    STAGE_AU(0,t+1,nb); STAGE_AU(1,t+1,nb); STAGE_BU(0,t+1,nb); STAGE_BU(1,t+1,nb);
    __builtin_amdgcn_s_setprio(1);
    MM0(0,0); MM0(0,1); MM0(1,0); MM0(1,1);
    MM0(2,0); MM0(2,1); MM0(3,0); MM0(3,1);
    __builtin_amdgcn_s_setprio(0);
    asm volatile("s_waitcnt vmcnt(4)" ::: "memory");
    BARRIER();
    #pragma unroll
    for (int rl=0;rl<2;++rl){ bF[rl][0]=RDB(b,rl+2,0); bF[rl][1]=RDB(b,rl+2,1); }
    STAGE_BU(2,t+1,nb); STAGE_BU(3,t+1,nb);
    __builtin_amdgcn_s_setprio(1);
    MM1(0,0); MM1(0,1); MM1(1,0); MM1(1,1);
    MM1(2,0); MM1(2,1); MM1(3,0); MM1(3,1);
    __builtin_amdgcn_s_setprio(0);
    asm volatile("s_waitcnt lgkmcnt(0)" ::: "memory");
    asm volatile("s_waitcnt vmcnt(2)" ::: "memory");
    BARRIER();
  }

  {
    const int b = (NTt-1) & 1;
    #pragma unroll
    for (int q=0;q<4;++q){ aF[q][0]=RDA(b,q,0); aF[q][1]=RDA(b,q,1); }
    #pragma unroll
    for (int rl=0;rl<2;++rl){ bF[rl][0]=RDB(b,rl,0); bF[rl][1]=RDB(b,rl,1); }
    __builtin_amdgcn_s_setprio(1);
    MM0(0,0); MM0(0,1); MM0(1,0); MM0(1,1);
    MM0(2,0); MM0(2,1); MM0(3,0); MM0(3,1);
    __builtin_amdgcn_s_setprio(0);
    asm volatile("s_waitcnt vmcnt(0)" ::: "memory");
    BARRIER();
    #pragma unroll
    for (int rl=0;rl<2;++rl){ bF[rl][0]=RDB(b,rl+2,0); bF[rl][1]=RDB(b,rl+2,1); }
    MM1(0,0); MM1(0,1); MM1(1,0); MM1(1,1);
    MM1(2,0); MM1(2,1); MM1(3,0); MM1(3,1);
  }

  float b0v[4][8];
  #pragma unroll
  for (int r=0;r<4;++r){
    int col = n0 + r*64 + wn*16 + (lane&15);
    const float4* bp = (const float4*)&B0[(size_t)col*8];
    float4 u0 = bp[0], u1 = bp[1];
    b0v[r][0]=u0.x; b0v[r][1]=u0.y; b0v[r][2]=u0.z; b0v[r][3]=u0.w;
    b0v[r][4]=u1.x; b0v[r][5]=u1.y; b0v[r][6]=u1.z; b0v[r][7]=u1.w;
  }
  #pragma unroll
  for (int q=0;q<4;++q){
    #pragma unroll
    for (int jj=0;jj<4;++jj){
      int row = m0 + q*32 + wm*16 + (lane>>4)*4 + jj;
      const float4* hp = (const float4*)&hmat[(size_t)row*8];
      float4 h0 = hp[0], h1 = hp[1];
      #pragma unroll
      for (int r=0;r<4;++r){
        float lor = h0.x*b0v[r][0]+h0.y*b0v[r][1]+h0.z*b0v[r][2]+h0.w*b0v[r][3]
                  + h1.x*b0v[r][4]+h1.y*b0v[r][5]+h1.z*b0v[r][6]+h1.w*b0v[r][7];
        int col = n0 + r*64 + wn*16 + (lane&15);
        float v = acc[q][r][jj] + 0.125f*lor;
        if (MODE==0) ((ushort_t*)C)[(size_t)row*N + col] = f2bf(v);
        else         ((float*)C)[(size_t)row*N + col]    = v;
      }
    }
  }
  #undef STAGE_AU
  #undef STAGE_BU
  #undef RDA
  #undef RDB
  #undef MM0
  #undef MM1
  #undef BARRIER
}

// ---------------------------------------------------------------- RoPE (in place on qkv bf16)
__global__ __launch_bounds__(256) void rope_kernel(ushort_t* __restrict__ qkv,
                                                   const float* __restrict__ cosb,
                                                   const float* __restrict__ sinb){
  int idx = blockIdx.x*256 + threadIdx.x;
  int d = idx & 7;
  int g = idx >> 3;
  int h_ = g & 15;
  int s  = (g>>4) & 1;
  int t  = (g>>5) & 511;
  int b  = g >> 14;
  size_t base = (size_t)(b*512 + t)*6144 + s*2048 + h_*128;
  float x1 = bf2f(qkv[base+d]), x2 = bf2f(qkv[base+d+8]);
  float c = cosb[t*8+d], sn = sinb[t*8+d];
  qkv[base+d]   = f2bf(x1*c - x2*sn);
  qkv[base+d+8] = f2bf(x2*c + x1*sn);
}

// ---------------------------------------------------------------- flash attention (KVBLK=64, swizzled LDS)
// grid (T/64, H, B); 256 threads = 4 waves; wave w owns q rows qb0+w*16..+15.
// Ks [64][128] bf16, 16B-chunk XOR-swizzle (low3 ^ row&7), staged via pre-swizzled gload_lds.
// Vt [128][64] transposed V, chunk ^= d&7 (scalar transposed writes, b128 reads 2-way).
// Pl per-wave [16][64], chunk ^= row&7.
__global__ __launch_bounds__(256) void attn_kernel(const ushort_t* __restrict__ qkv,
                                                   ushort_t* __restrict__ y){
  __shared__ __align__(16) ushort_t Ks[64*128];
  __shared__ __align__(16) ushort_t Vt[128*64];
  __shared__ __align__(16) ushort_t Pl[4][16*64];

  const int qt = blockIdx.x, hh = blockIdx.y, b = blockIdx.z;
  const int tid = threadIdx.x, lane = tid & 63, w = tid >> 6, g = lane >> 4;
  const int qb0 = qt*64;
  const int row_base = b*512;
  const int qoff = hh*128;
  const int koff = 2048 + hh*128;
  const int voff = 4096 + hh*128;
  const float scale = 0.08838834764831845f;

  // Q fragments (A-operand), once
  short8 qf[4];
  {
    int qr = qb0 + w*16 + (lane & 15);
    const ushort_t* qp = qkv + (size_t)(row_base + qr)*6144 + qoff + g*8;
    #pragma unroll
    for (int kc=0;kc<4;++kc) qf[kc] = *(const short8*)(qp + kc*32);
  }

  // staging geometry (block-wide)
  const int krow = tid >> 4;                 // 0..15 (K: +16 per issue)
  const int kc_  = tid & 15;
  const int kcs  = (kc_ & 8) | ((kc_ ^ (krow & 7)) & 7);
  const int vr   = tid >> 2;                 // 0..63
  const int vd0  = (tid & 3) * 32;
  const int vrhi = vr >> 3, vrlo = vr & 7;

  f32x4 o[8] = {};
  float mrow[4] = {-1e30f,-1e30f,-1e30f,-1e30f};
  float lrow[4] = {0,0,0,0};

  for (int t = 0; t <= qt; ++t){
    const int kv0 = t*64;
    __syncthreads();   // all reads of Ks/Vt(t-1) done
    // --- stage K via swizzled-source gload_lds (async under V transpose)
    {
      const ushort_t* kg = qkv + (size_t)(row_base + kv0 + krow)*6144 + koff + kcs*8;
      #pragma unroll
      for (int i=0;i<4;++i)
        __builtin_amdgcn_global_load_lds(AS1(kg + (size_t)(i*16)*6144),
                                         AS3((char*)Ks + i*4096 + tid*16), 16, 0, 0);
    }
    // --- stage V transposed (reg->scalar swizzled writes)
    {
      const ushort_t* vg = qkv + (size_t)(row_base + kv0 + vr)*6144 + voff + vd0;
      short8 vv0 = ((const short8*)vg)[0];
      short8 vv1 = ((const short8*)vg)[1];
      short8 vv2 = ((const short8*)vg)[2];
      short8 vv3 = ((const short8*)vg)[3];
      #pragma unroll
      for (int ii=0;ii<8;++ii){
        int sw = (vrhi ^ ii) << 3;
        Vt[(vd0 + ii     )*64 + sw + vrlo] = (ushort_t)vv0[ii];
        Vt[(vd0 + 8 + ii )*64 + sw + vrlo] = (ushort_t)vv1[ii];
        Vt[(vd0 + 16 + ii)*64 + sw + vrlo] = (ushort_t)vv2[ii];
        Vt[(vd0 + 24 + ii)*64 + sw + vrlo] = (ushort_t)vv3[ii];
      }
    }
    __syncthreads();   // staging visible (vmcnt/lgkm drained by sync)

    // --- QK^T: 4 col-groups x 4 k-chunks
    f32x4 s4[4] = {};
    #pragma unroll
    for (int cg=0;cg<4;++cg){
      const int row = cg*16 + (lane&15);
      const int rx = row & 7;
      #pragma unroll
      for (int kc=0;kc<4;++kc){
        const int ch = kc*4 + g;
        const short8 kfv = *(const short8*)&Ks[row*128 + (((ch&8)|((ch^rx)&7))<<3)];
        s4[cg] = __builtin_amdgcn_mfma_f32_16x16x32_bf16(qf[kc], kfv, s4[cg], 0, 0, 0);
      }
    }

    // --- online softmax (rows g*4+j)
    const bool diag = (t == qt);
    float fac[4], p0[4], p1[4], p2[4], p3[4];
    #pragma unroll
    for (int j=0;j<4;++j){
      float a0 = s4[0][j]*scale, a1 = s4[1][j]*scale, a2 = s4[2][j]*scale, a3 = s4[3][j]*scale;
      if (diag){
        int q_abs = qb0 + w*16 + g*4 + j;
        int c0 = kv0 + (lane&15);
        if (c0      > q_abs) a0 = -1e30f;
        if (c0 + 16 > q_abs) a1 = -1e30f;
        if (c0 + 32 > q_abs) a2 = -1e30f;
        if (c0 + 48 > q_abs) a3 = -1e30f;
      }
      float mx = fmaxf(fmaxf(a0,a1), fmaxf(a2,a3));
      #pragma unroll
      for (int d=1; d<16; d<<=1) mx = fmaxf(mx, __shfl_xor(mx, d, 16));
      float mn = fmaxf(mrow[j], mx);
      float f  = __expf(mrow[j] - mn);
      mrow[j] = mn; fac[j] = f;
      p0[j] = __expf(a0 - mn); p1[j] = __expf(a1 - mn);
      p2[j] = __expf(a2 - mn); p3[j] = __expf(a3 - mn);
      float rs = p0[j] + p1[j] + p2[j] + p3[j];
      #pragma unroll
      for (int d=1; d<16; d<<=1) rs += __shfl_xor(rs, d, 16);
      lrow[j] = lrow[j]*f + rs;
    }
    #pragma unroll
    for (int n=0;n<8;++n){
      #pragma unroll
      for (int j=0;j<4;++j) o[n][j] *= fac[j];
    }

    // --- P to per-wave swizzled LDS (row = g*4+j, col = cg*16+(lane&15))
    {
      ushort_t* plw = &Pl[w][0];
      #pragma unroll
      for (int j=0;j<4;++j){
        const int prow = g*4 + j;
        const int rx = prow & 7;
        const int cl = (lane&15)>>3, c7 = lane&7;
        plw[prow*64 + (((0*2+cl)^rx)<<3) + c7] = f2bf(p0[j]);
        plw[prow*64 + (((1*2+cl)^rx)<<3) + c7] = f2bf(p1[j]);
        plw[prow*64 + (((2*2+cl)^rx)<<3) + c7] = f2bf(p2[j]);
        plw[prow*64 + (((3*2+cl)^rx)<<3) + c7] = f2bf(p3[j]);
      }
    }
    // --- PV: o[n] += P(16x64) @ V(64 x d16)
    {
      const ushort_t* plw = &Pl[w][0];
      const int rowP = lane & 15, rxp = rowP & 7;
      const short8 pf0 = *(const short8*)&plw[rowP*64 + (((g  )^rxp)<<3)];
      const short8 pf1 = *(const short8*)&plw[rowP*64 + (((4+g)^rxp)<<3)];
      #pragma unroll
      for (int n=0;n<8;++n){
        const int d = n*16 + (lane&15);
        const int dx = d & 7;
        const short8 vf0 = *(const short8*)&Vt[d*64 + (((g  )^dx)<<3)];
        const short8 vf1 = *(const short8*)&Vt[d*64 + (((4+g)^dx)<<3)];
        o[n] = __builtin_amdgcn_mfma_f32_16x16x32_bf16(pf0, vf0, o[n], 0, 0, 0);
        o[n] = __builtin_amdgcn_mfma_f32_16x16x32_bf16(pf1, vf1, o[n], 0, 0, 0);
      }
    }
  }

  // --- epilogue
  #pragma unroll
  for (int j=0;j<4;++j){
    float inv = 1.0f / lrow[j];
    int qr = qb0 + w*16 + g*4 + j;
    #pragma unroll
    for (int n=0;n<8;++n)
      y[(size_t)(row_base+qr)*2048 + hh*128 + n*16 + (lane&15)] = f2bf(o[n][j]*inv);
  }
}

// ---------------------------------------------------------------- launch
extern "C" void kernel_launch(void* const* d_in, const int* in_sizes, int n_in,
                              void* d_out, int out_size, void* d_ws, size_t ws_size,
                              hipStream_t stream){
  const float* x       = (const float*)d_in[0];
  const float* Wqkv    = (const float*)d_in[1];
  const float* A0_qkv  = (const float*)d_in[2];
  const float* B0_qkv  = (const float*)d_in[3];
  const float* da_qkv  = (const float*)d_in[4];
  const float* db_qkv  = (const float*)d_in[5];
  const float* Wout    = (const float*)d_in[6];
  const float* A0_out  = (const float*)d_in[7];
  const float* B0_out  = (const float*)d_in[8];
  const float* da_out  = (const float*)d_in[9];
  const float* db_out  = (const float*)d_in[10];
  const float* cosb    = (const float*)d_in[11];
  const float* sinb    = (const float*)d_in[12];
  float* out = (float*)d_out;

  char* ws = (char*)d_ws;
  ushort_t* x_bf    = (ushort_t*)(ws);
  ushort_t* wqkv_bf = (ushort_t*)(ws + 16777216);
  ushort_t* wout_bf = (ushort_t*)(ws + 41943040);
  ushort_t* qkv_bf  = (ushort_t*)(ws + 50331648);
  ushort_t* y_bf    = (ushort_t*)(ws + 100663296);
  float*    h_qkv   = (float*)   (ws + 117440512);
  float*    h_out   = (float*)   (ws + 117571584);

  const int M = 4096;
  const int C = 2048;
  const int N3 = 6144;

  conv_f2b<<<8192, 256, 0, stream>>>(x,    x_bf,    M*C);
  conv_f2b<<<12288,256, 0, stream>>>(Wqkv, wqkv_bf, N3*C);
  conv_f2b<<<4096, 256, 0, stream>>>(Wout, wout_bf, C*C);

  lora_h<false><<<M, 256, 0, stream>>>(x, A0_qkv, da_qkv, db_qkv, h_qkv, C);

  gemm128x256_lora<0><<<(M/128)*(N3/256), 512, 0, stream>>>(x_bf, wqkv_bf, h_qkv, B0_qkv,
                                                            qkv_bf, M, N3, C);

  rope_kernel<<<4096, 256, 0, stream>>>(qkv_bf, cosb, sinb);

  attn_kernel<<<dim3(8, 16, 8), 256, 0, stream>>>(qkv_bf, y_bf);

  lora_h<true><<<M, 256, 0, stream>>>(y_bf, A0_out, da_out, db_out, h_out, C);

  gemm128x256_lora<1><<<(M/128)*(C/256), 512, 0, stream>>>(y_bf, wout_bf, h_out, B0_out,
                                                           out, M, C, C);
}